// Round 1
// baseline (380.709 us; speedup 1.0000x reference)
//
#include <hip/hip_runtime.h>
#include <stddef.h>

// Problem constants (from reference): B=32, T=4096, D=512, G=8, OUT=512
#define B_    32
#define T_    4096
#define D_    512
#define G_    8
#define OUT_  512
#define TC_   64              // token chunks over T
#define CHUNK_ (T_ / TC_)     // 64 tokens per chunk
#define DC_   4               // d-chunks in the GEMM stage

typedef float f4 __attribute__((ext_vector_type(4)));

// ---------------------------------------------------------------------------
// k1: per-(chunk, batch) partial segmented sums + counts.
// 128 threads, each owns a float4 slice of D (128*4 = 512). Token loop is
// block-uniform: type[t] and pad[b,t] are scalar, so the switch is a uniform
// s_cbranch chain and padded rows skip the 2KB HBM fetch entirely (~50%).
// ---------------------------------------------------------------------------
__global__ __launch_bounds__(128) void k1_partials(
    const float* __restrict__ batch, const int* __restrict__ types,
    const void* __restrict__ mask, float* __restrict__ partials,
    int* __restrict__ cpart)
{
    const int tc  = blockIdx.x;
    const int b   = blockIdx.y;
    const int tid = threadIdx.x;

    // --- mask dtype detection: bool may arrive as uint8 or int32 ---
    const int* mi = (const int*)mask;
    unsigned big = 0;
    #pragma unroll
    for (int i = 0; i < 64; ++i) big |= (unsigned)mi[i];
    const bool is_u8 = (big > 1u);   // int32 0/1 mask can never exceed 1
    const unsigned char* m8 = (const unsigned char*)mask;

    f4 acc[G_];
    int cnt[G_];
    #pragma unroll
    for (int g = 0; g < G_; ++g) { acc[g] = (f4){0.f,0.f,0.f,0.f}; cnt[g] = 0; }

    const int t0 = tc * CHUNK_;
    const float* bp = batch + ((size_t)b * T_ + (size_t)t0) * D_ + (tid << 2);

    for (int i = 0; i < CHUNK_; ++i) {
        const int t = t0 + i;
        const int g = types[t];                       // uniform
        const bool pad = is_u8 ? (m8[(size_t)b * T_ + t] != 0)
                               : (mi[(size_t)b * T_ + t] != 0);  // uniform
        if (!pad) {
            f4 v = *(const f4*)(bp + (size_t)i * D_);
            switch (g) {                               // uniform branch
                case 0: acc[0] += v; cnt[0]++; break;
                case 1: acc[1] += v; cnt[1]++; break;
                case 2: acc[2] += v; cnt[2]++; break;
                case 3: acc[3] += v; cnt[3]++; break;
                case 4: acc[4] += v; cnt[4]++; break;
                case 5: acc[5] += v; cnt[5]++; break;
                case 6: acc[6] += v; cnt[6]++; break;
                default: acc[7] += v; cnt[7]++; break;
            }
        }
    }

    float* pp = partials + ((size_t)(tc * B_ + b) * G_) * D_ + (tid << 2);
    #pragma unroll
    for (int g = 0; g < G_; ++g)
        *(f4*)(pp + (size_t)g * D_) = acc[g];

    if (tid == 0) {
        int* cp = cpart + (tc * B_ + b) * G_;
        #pragma unroll
        for (int g = 0; g < G_; ++g) cp[g] = cnt[g];
    }
}

// ---------------------------------------------------------------------------
// k2a: reduce over TC chunks -> means[b,g,:], divide by count, empty -> 0.
// Grid (G, B), 128 threads (float4 each).
// ---------------------------------------------------------------------------
__global__ __launch_bounds__(128) void k2a_means(
    const float* __restrict__ partials, const int* __restrict__ cpart,
    float* __restrict__ means)
{
    const int g = blockIdx.x, b = blockIdx.y, tid = threadIdx.x;

    int cnt = 0;
    for (int tc = 0; tc < TC_; ++tc) cnt += cpart[(tc * B_ + b) * G_ + g];

    f4 s = (f4){0.f,0.f,0.f,0.f};
    for (int tc = 0; tc < TC_; ++tc)
        s += *(const f4*)(partials + ((size_t)(tc * B_ + b) * G_ + g) * D_ + (tid << 2));

    f4 m;
    if (cnt > 0) {
        const float inv = 1.0f / (float)cnt;
        m = s * inv;
    } else {
        m = (f4){0.f,0.f,0.f,0.f};
    }
    *(f4*)(means + ((size_t)b * G_ + g) * D_ + (tid << 2)) = m;
}

// ---------------------------------------------------------------------------
// k2b: out_partial[dc][b,g,o] = means[b,g,d0:d0+128] @ W[g,d0:d0+128,o]
// Grid (OC=8, DC=4, G=8) = 256 blocks, 256 threads.
// Lane layout: o = oc*64 + (tid&63); each wave owns brow = tid>>6, covering
// b = brow*8 .. brow*8+7 via wave-uniform scalar loads of means.
// W is read exactly once across the grid (8 MB).
// ---------------------------------------------------------------------------
__global__ __launch_bounds__(256) void k2b_gemm(
    const float* __restrict__ means, const float* __restrict__ W,
    float* __restrict__ opart)
{
    const int oc = blockIdx.x, dc = blockIdx.y, g = blockIdx.z;
    const int o = oc * 64 + (threadIdx.x & 63);
    const int brow = __builtin_amdgcn_readfirstlane((int)(threadIdx.x >> 6));
    const int d0 = dc * 128;

    float acc[8];
    #pragma unroll
    for (int i = 0; i < 8; ++i) acc[i] = 0.0f;

    const float* wp = W + ((size_t)g * D_ + d0) * OUT_ + o;
    const float* mp = means + ((size_t)(brow * 8) * G_ + g) * D_ + d0;

    #pragma unroll 4
    for (int dd = 0; dd < 128; ++dd) {
        const float w = wp[(size_t)dd * OUT_];
        #pragma unroll
        for (int i = 0; i < 8; ++i)
            acc[i] += w * mp[(size_t)i * (G_ * D_) + dd];  // wave-uniform s_load
    }

    float* op = opart + (size_t)dc * (B_ * G_ * OUT_)
                      + ((size_t)(brow * 8) * G_ + g) * OUT_ + o;
    #pragma unroll
    for (int i = 0; i < 8; ++i)
        op[(size_t)i * (G_ * OUT_)] = acc[i];
}

// ---------------------------------------------------------------------------
// k2c: out = sum_dc opart[dc] + bias. 131072 floats; 128 blocks x 256 thr x f4.
// ---------------------------------------------------------------------------
__global__ __launch_bounds__(256) void k2c_final(
    const float* __restrict__ opart, const float* __restrict__ bias,
    float* __restrict__ out)
{
    const int idx = (int)((blockIdx.x * 256 + threadIdx.x) << 2);
    f4 s = *(const f4*)(bias + (idx & (G_ * OUT_ - 1)));
    #pragma unroll
    for (int dc = 0; dc < DC_; ++dc)
        s += *(const f4*)(opart + (size_t)dc * (B_ * G_ * OUT_) + idx);
    *(f4*)(out + idx) = s;
}

// ---------------------------------------------------------------------------
extern "C" void kernel_launch(void* const* d_in, const int* in_sizes, int n_in,
                              void* d_out, int out_size, void* d_ws, size_t ws_size,
                              hipStream_t stream)
{
    const float* batch = (const float*)d_in[0];   // [B,T,D] f32
    const float* W     = (const float*)d_in[1];   // [G,D,OUT] f32
    const float* bias  = (const float*)d_in[2];   // [G,OUT] f32
    const int*   types = (const int*)d_in[3];     // [T] i32
    const void*  mask  = d_in[4];                 // [B,T] bool (u8 or i32 - detected)
    float* out = (float*)d_out;                   // [B,G,OUT] f32

    // Workspace layout (floats): partials | cpart | means | opart  (~34.6 MB)
    float* ws = (float*)d_ws;
    const size_t P = (size_t)TC_ * B_ * G_ * D_;        // 8,388,608
    float* partials = ws;
    int*   cpart    = (int*)(ws + P);                    // TC*B*G ints
    float* means    = ws + P + (size_t)TC_ * B_ * G_;    // B*G*D
    float* opart    = means + (size_t)B_ * G_ * D_;      // DC*B*G*OUT

    k1_partials<<<dim3(TC_, B_), 128, 0, stream>>>(batch, types, mask, partials, cpart);
    k2a_means  <<<dim3(G_, B_), 128, 0, stream>>>(partials, cpart, means);
    k2b_gemm   <<<dim3(OUT_ / 64, DC_, G_), 256, 0, stream>>>(means, W, opart);
    k2c_final  <<<(B_ * G_ * OUT_) / (256 * 4), 256, 0, stream>>>(opart, bias, out);
}

// Round 2
// 368.193 us; speedup vs baseline: 1.0340x; 1.0340x over previous
//
#include <hip/hip_runtime.h>
#include <stddef.h>

// Problem constants: B=32, T=4096, D=512, G=8, OUT=512
#define B_    32
#define T_    4096
#define D_    512
#define G_    8
#define OUT_  512
#define TC_   32              // token chunks over T
#define CHUNK_ (T_ / TC_)     // 128 tokens per chunk == blockDim
#define DC_   4               // d-chunks in the GEMM stage

typedef float f4 __attribute__((ext_vector_type(4)));

// ---------------------------------------------------------------------------
// k1: compact-then-stream segmented partial sums.
// Block = (chunk tc, batch b), 128 threads (2 waves), each thread owns a
// float4 slice of D. Phase 1: one coalesced mask+type read, ballot/prefix
// compaction of valid tokens into an LDS list. Phase 2: dense unroll-4 load
// loop (4 outstanding 2KB rows/wave -> BW-bound, not latency-bound).
// ---------------------------------------------------------------------------
__global__ __launch_bounds__(128) void k1_partials(
    const float* __restrict__ batch, const int* __restrict__ types,
    const void* __restrict__ mask, float* __restrict__ partials,
    int* __restrict__ cpart)
{
    const int tc  = blockIdx.x;
    const int b   = blockIdx.y;
    const int tid = threadIdx.x;
    const int lane = tid & 63;
    const int w    = tid >> 6;

    // --- mask dtype detection (bool may arrive as uint8 or int32) ---
    const int* mi = (const int*)mask;
    unsigned big = 0;
    #pragma unroll
    for (int i = 0; i < 64; ++i) big |= (unsigned)mi[i];
    const bool is_u8 = (big > 1u);
    const unsigned char* m8 = (const unsigned char*)mask;

    // --- phase 1: compaction of this chunk's 128 tokens ---
    const int t0 = tc * CHUNK_;
    const int t  = t0 + tid;
    const int grp = types[t];                      // coalesced
    const bool pad = is_u8 ? (m8[(size_t)b * T_ + t] != 0)
                           : (mi[(size_t)b * T_ + t] != 0);
    const bool valid = !pad;

    __shared__ int list[CHUNK_];
    __shared__ int wtot[2];

    unsigned long long bal = __ballot(valid);
    int pre = __popcll(bal & ((1ull << lane) - 1ull));
    if (lane == 0) wtot[w] = __popcll(bal);
    __syncthreads();
    const int base = (w == 1) ? wtot[0] : 0;
    if (valid) list[base + pre] = tid | (grp << 8);
    const int nvalid = wtot[0] + wtot[1];
    __syncthreads();

    // --- phase 2: dense streaming accumulate ---
    f4 acc[G_];
    int cnt[G_];
    #pragma unroll
    for (int g = 0; g < G_; ++g) { acc[g] = (f4){0.f,0.f,0.f,0.f}; cnt[g] = 0; }

    const float* bp = batch + ((size_t)b * T_ + (size_t)t0) * D_ + (tid << 2);

    #define ACCUM(V, E) do {                                              \
        const int gg = __builtin_amdgcn_readfirstlane((E) >> 8);          \
        switch (gg) {                                                     \
            case 0: acc[0] += (V); cnt[0]++; break;                       \
            case 1: acc[1] += (V); cnt[1]++; break;                       \
            case 2: acc[2] += (V); cnt[2]++; break;                       \
            case 3: acc[3] += (V); cnt[3]++; break;                       \
            case 4: acc[4] += (V); cnt[4]++; break;                       \
            case 5: acc[5] += (V); cnt[5]++; break;                       \
            case 6: acc[6] += (V); cnt[6]++; break;                       \
            default: acc[7] += (V); cnt[7]++; break;                      \
        }                                                                 \
    } while (0)

    int j = 0;
    for (; j + 4 <= nvalid; j += 4) {
        const int e0 = __builtin_amdgcn_readfirstlane(list[j + 0]);
        const int e1 = __builtin_amdgcn_readfirstlane(list[j + 1]);
        const int e2 = __builtin_amdgcn_readfirstlane(list[j + 2]);
        const int e3 = __builtin_amdgcn_readfirstlane(list[j + 3]);
        // issue all 4 row loads before any use -> 4 outstanding per wave
        f4 v0 = *(const f4*)(bp + (size_t)(e0 & 0xff) * D_);
        f4 v1 = *(const f4*)(bp + (size_t)(e1 & 0xff) * D_);
        f4 v2 = *(const f4*)(bp + (size_t)(e2 & 0xff) * D_);
        f4 v3 = *(const f4*)(bp + (size_t)(e3 & 0xff) * D_);
        ACCUM(v0, e0); ACCUM(v1, e1); ACCUM(v2, e2); ACCUM(v3, e3);
    }
    for (; j < nvalid; ++j) {
        const int e0 = __builtin_amdgcn_readfirstlane(list[j]);
        f4 v0 = *(const f4*)(bp + (size_t)(e0 & 0xff) * D_);
        ACCUM(v0, e0);
    }
    #undef ACCUM

    float* pp = partials + ((size_t)(tc * B_ + b) * G_) * D_ + (tid << 2);
    #pragma unroll
    for (int g = 0; g < G_; ++g)
        *(f4*)(pp + (size_t)g * D_) = acc[g];

    if (tid == 0) {
        int* cp = cpart + (tc * B_ + b) * G_;
        #pragma unroll
        for (int g = 0; g < G_; ++g) cp[g] = cnt[g];
    }
}

// ---------------------------------------------------------------------------
// k2a: reduce over TC chunks -> means[b,g,:]. Grid (G,B), 128 threads.
// ---------------------------------------------------------------------------
__global__ __launch_bounds__(128) void k2a_means(
    const float* __restrict__ partials, const int* __restrict__ cpart,
    float* __restrict__ means)
{
    const int g = blockIdx.x, b = blockIdx.y, tid = threadIdx.x;

    int cnt = 0;
    #pragma unroll
    for (int tc = 0; tc < TC_; ++tc) cnt += cpart[(tc * B_ + b) * G_ + g];

    f4 s = (f4){0.f,0.f,0.f,0.f};
    #pragma unroll 8
    for (int tc = 0; tc < TC_; ++tc)
        s += *(const f4*)(partials + ((size_t)(tc * B_ + b) * G_ + g) * D_ + (tid << 2));

    f4 m = (f4){0.f,0.f,0.f,0.f};
    if (cnt > 0) m = s * (1.0f / (float)cnt);
    *(f4*)(means + ((size_t)b * G_ + g) * D_ + (tid << 2)) = m;
}

// ---------------------------------------------------------------------------
// k2b: opart[dc][b,g,o] = means[b,g,d0:d0+128] @ W[g,d0:d0+128,o]
// Grid (OC=8, DC=4, G=8), 256 threads. o = oc*64+(tid&63); wave brow covers
// b = brow*8..+7 via scalar (readfirstlane-based) means loads.
// ---------------------------------------------------------------------------
__global__ __launch_bounds__(256) void k2b_gemm(
    const float* __restrict__ means, const float* __restrict__ W,
    float* __restrict__ opart)
{
    const int oc = blockIdx.x, dc = blockIdx.y, g = blockIdx.z;
    const int o = oc * 64 + (threadIdx.x & 63);
    const int brow = __builtin_amdgcn_readfirstlane((int)(threadIdx.x >> 6));
    const int d0 = dc * 128;

    float acc[8];
    #pragma unroll
    for (int i = 0; i < 8; ++i) acc[i] = 0.0f;

    const float* wp = W + ((size_t)g * D_ + d0) * OUT_ + o;
    const float* mp = means + ((size_t)(brow * 8) * G_ + g) * D_ + d0;

    #pragma unroll 4
    for (int dd = 0; dd < 128; ++dd) {
        const float wv = wp[(size_t)dd * OUT_];
        #pragma unroll
        for (int i = 0; i < 8; ++i)
            acc[i] += wv * mp[(size_t)i * (G_ * D_) + dd];  // scalar loads
    }

    float* op = opart + (size_t)dc * (B_ * G_ * OUT_)
                      + ((size_t)(brow * 8) * G_ + g) * OUT_ + o;
    #pragma unroll
    for (int i = 0; i < 8; ++i)
        op[(size_t)i * (G_ * OUT_)] = acc[i];
}

// ---------------------------------------------------------------------------
// k2c: out = sum_dc opart[dc] + bias.
// ---------------------------------------------------------------------------
__global__ __launch_bounds__(256) void k2c_final(
    const float* __restrict__ opart, const float* __restrict__ bias,
    float* __restrict__ out)
{
    const int idx = (int)((blockIdx.x * 256 + threadIdx.x) << 2);
    f4 s = *(const f4*)(bias + (idx & (G_ * OUT_ - 1)));
    #pragma unroll
    for (int dc = 0; dc < DC_; ++dc)
        s += *(const f4*)(opart + (size_t)dc * (B_ * G_ * OUT_) + idx);
    *(f4*)(out + idx) = s;
}

// ---------------------------------------------------------------------------
extern "C" void kernel_launch(void* const* d_in, const int* in_sizes, int n_in,
                              void* d_out, int out_size, void* d_ws, size_t ws_size,
                              hipStream_t stream)
{
    const float* batch = (const float*)d_in[0];   // [B,T,D] f32
    const float* W     = (const float*)d_in[1];   // [G,D,OUT] f32
    const float* bias  = (const float*)d_in[2];   // [G,OUT] f32
    const int*   types = (const int*)d_in[3];     // [T] i32
    const void*  mask  = d_in[4];                 // [B,T] bool (u8/i32 detected)
    float* out = (float*)d_out;                   // [B,G,OUT] f32

    float* ws = (float*)d_ws;
    const size_t P = (size_t)TC_ * B_ * G_ * D_;         // 4,194,304 floats
    float* partials = ws;
    int*   cpart    = (int*)(ws + P);                    // TC*B*G ints
    float* means    = ws + P + (size_t)TC_ * B_ * G_;    // B*G*D
    float* opart    = means + (size_t)B_ * G_ * D_;      // DC*B*G*OUT

    k1_partials<<<dim3(TC_, B_), CHUNK_, 0, stream>>>(batch, types, mask, partials, cpart);
    k2a_means  <<<dim3(G_, B_), 128, 0, stream>>>(partials, cpart, means);
    k2b_gemm   <<<dim3(OUT_ / 64, DC_, G_), 256, 0, stream>>>(means, W, opart);
    k2c_final  <<<(B_ * G_ * OUT_) / (256 * 4), 256, 0, stream>>>(opart, bias, out);
}